// Round 7
// baseline (213.390 us; speedup 1.0000x reference)
//
#include <hip/hip_runtime.h>

// Problem constants
#define BATCH 32
#define CCH 3
#define HW_TEX (512 * 512)
#define N_TEX (HW_TEX * CCH)          // 786432 per-sample flat texture (channels-last)
#define OH 128
#define OW 64
#define P_OUT (OH * OW)               // 8192
#define M_OUT (P_OUT * CCH)           // 24576 rows per sample (channels-last)
#define NNZ 98304
#define OUT_ELEMS (BATCH * M_OUT)     // 786432

// Geometry: grid 512 (2 blocks/CU), per XCD 64 slots = 4 chunks x 16 segs.
#define NCH 4                          // row chunks per sample
#define RPCH (M_OUT / NCH)             // 6144 rows -> 24 KB LDS
#define NE 16                          // nnz segments
#define SEGE (NNZ / NE)                // 6144 nnz per block-round
#define TB 1024
#define NROUND 4                       // sample phases per XCD

#define WS_NEED ((size_t)BATCH * NCH * NE * RPCH * 4)   // 50.3 MB

// ---------- scan: chunk-specialized, predicated gather, XCD-sample-phased ----
// blk: xcd = blk&7, slot = blk>>3 (0..63) -> chunk c = slot&3, seg e = slot>>2.
// Round rnd: all 64 blocks of an XCD scan sample s = rnd*8+xcd (L2-resident).
// Per thread per round: 6 nnz = int4 (4) + int2 (2) batched index loads
// (unconditional, full MLP); gather + ds_add are exec-mask predicated so
// inactive lanes issue NO memory requests.
__global__ __launch_bounds__(TB) void scan_pred_kernel(
    const float* __restrict__ x,
    const int*   __restrict__ rows,
    const int*   __restrict__ cols,
    const float* __restrict__ vals,
    float* __restrict__ partial) {
    __shared__ __align__(16) float acc[RPCH];

    const int blk  = blockIdx.x;
    const int xcd  = blk & 7;
    const int slot = blk >> 3;
    const int c    = slot & (NCH - 1);
    const int e    = slot >> 2;
    const int t    = threadIdx.x;
    const int rbase = c * RPCH;

    for (int rnd = 0; rnd < NROUND; ++rnd) {
        const int s = rnd * 8 + xcd;

        // zero 24 KB: 3 x float2 per thread
        float2* acc2 = reinterpret_cast<float2*>(acc);
#pragma unroll
        for (int j = 0; j < RPCH / 2 / TB; ++j)
            acc2[t + j * TB] = make_float2(0.f, 0.f);
        __syncthreads();

        const size_t off = (size_t)s * NNZ + (size_t)e * SEGE;
        const float* xs = x + (size_t)s * N_TEX;

        // Batched unconditional index loads: 4 nnz via int4 + 2 nnz via int2.
        int4   ra = reinterpret_cast<const int4*>(rows + off)[t];
        int4   ca = reinterpret_cast<const int4*>(cols + off)[t];
        float4 va = reinterpret_cast<const float4*>(vals + off)[t];
        int2   rb = reinterpret_cast<const int2*>(rows + off + 4096)[t];
        int2   cb = reinterpret_cast<const int2*>(cols + off + 4096)[t];
        float2 vb = reinterpret_cast<const float2*>(vals + off + 4096)[t];

        int   ri[6] = {ra.x, ra.y, ra.z, ra.w, rb.x, rb.y};
        int   ci[6] = {ca.x, ca.y, ca.z, ca.w, cb.x, cb.y};
        float vi[6] = {va.x, va.y, va.z, va.w, vb.x, vb.y};

#pragma unroll
        for (int k = 0; k < 6; ++k) {
            unsigned lr = (unsigned)(ri[k] - rbase);
            if (lr < (unsigned)RPCH) {          // exec-masked: inactive lanes
                int gi = (ci[k] % CCH) * HW_TEX + ci[k] / CCH;
                atomicAdd(&acc[lr], vi[k] * xs[gi]);   // issue no mem requests
            }
        }
        __syncthreads();

        // dump 24 KB partial, coalesced float2
        float2* pp = reinterpret_cast<float2*>(
            partial + (((size_t)s * NCH + c) * NE + e) * RPCH);
#pragma unroll
        for (int j = 0; j < RPCH / 2 / TB; ++j)
            pp[t + j * TB] = acc2[t + j * TB];
        __syncthreads();
    }
}

// ---------- reduce: sum NE partials per (s,chunk,row), CHW transform, mask --
__global__ __launch_bounds__(256) void reduce_chunk_kernel(
    const float* __restrict__ partial,
    const float* __restrict__ mask,
    float* __restrict__ out) {
    int tid = blockIdx.x * 256 + threadIdx.x;       // over OUT_ELEMS/4
    if (tid >= OUT_ELEMS / 4) return;
    int s    = tid / (M_OUT / 4);
    int rcl4 = (tid % (M_OUT / 4)) * 4;             // 4 consecutive channels-last rows
    int c    = rcl4 / RPCH;                         // chunk (RPCH % 4 == 0)
    int lr4  = rcl4 % RPCH;

    const float4* pp = reinterpret_cast<const float4*>(
        partial + (((size_t)s * NCH + c) * NE) * RPCH + lr4);
    float4 sum = make_float4(0.f, 0.f, 0.f, 0.f);
#pragma unroll
    for (int e = 0; e < NE; ++e) {
        float4 p = pp[(size_t)e * (RPCH / 4)];
        sum.x += p.x; sum.y += p.y; sum.z += p.z; sum.w += p.w;
    }
    float* ob = out + (size_t)s * M_OUT;
    ob[(rcl4 + 0) % CCH * P_OUT + (rcl4 + 0) / CCH] = sum.x;
    ob[(rcl4 + 1) % CCH * P_OUT + (rcl4 + 1) / CCH] = sum.y;
    ob[(rcl4 + 2) % CCH * P_OUT + (rcl4 + 2) / CCH] = sum.z;
    ob[(rcl4 + 3) % CCH * P_OUT + (rcl4 + 3) / CCH] = sum.w;
    reinterpret_cast<float4*>(out + OUT_ELEMS)[tid] =
        reinterpret_cast<const float4*>(mask)[tid];
}

// ---------- fallback (R2): no workspace needed ------------------------------
#define CHUNKS 8
#define RPC (M_OUT / CHUNKS)
#define BLOCK 1024
__global__ __launch_bounds__(BLOCK) void spmm_chunk_kernel(
    const float* __restrict__ x,
    const int*   __restrict__ rows,
    const int*   __restrict__ cols,
    const float* __restrict__ vals,
    const float* __restrict__ mask,
    float* __restrict__ out) {
    __shared__ float acc[RPC];
    const int blk = blockIdx.x;
    const int s   = blk / CHUNKS;
    const int c   = blk % CHUNKS;
    const int t   = threadIdx.x;
    const int rbase = c * RPC;
#pragma unroll
    for (int j = 0; j < RPC / BLOCK; ++j) acc[t + j * BLOCK] = 0.0f;
    __syncthreads();
    const int*   rs = rows + (size_t)s * NNZ;
    const int*   cs = cols + (size_t)s * NNZ;
    const float* vs = vals + (size_t)s * NNZ;
    const float* xs = x    + (size_t)s * N_TEX;
#pragma unroll 4
    for (int i = t; i < NNZ; i += BLOCK) {
        int r = rs[i];
        unsigned lr = (unsigned)(r - rbase);
        if (lr < (unsigned)RPC) {
            int   col = cs[i];
            float v   = vs[i];
            atomicAdd(&acc[lr], v * xs[(col % CCH) * HW_TEX + col / CCH]);
        }
    }
    __syncthreads();
    const size_t outbase = (size_t)s * M_OUT;
#pragma unroll
    for (int ch = 0; ch < CCH; ++ch)
        out[outbase + (size_t)ch * P_OUT + c * (P_OUT / CHUNKS) + t] = acc[t * CCH + ch];
    {
        float* mout = out + OUT_ELEMS;
        const int base = blk * RPC;
#pragma unroll
        for (int j = 0; j < RPC / BLOCK; ++j)
            mout[base + j * BLOCK + t] = mask[base + j * BLOCK + t];
    }
}

extern "C" void kernel_launch(void* const* d_in, const int* in_sizes, int n_in,
                              void* d_out, int out_size, void* d_ws, size_t ws_size,
                              hipStream_t stream) {
    const float* x    = (const float*)d_in[0];
    const int*   rows = (const int*)  d_in[1];
    const int*   cols = (const int*)  d_in[2];
    const float* vals = (const float*)d_in[3];
    const float* mask = (const float*)d_in[4];
    float* out = (float*)d_out;
    int rgrid = (OUT_ELEMS / 4 + 255) / 256;   // 768

    if (ws_size >= WS_NEED) {
        float* partial = (float*)d_ws;
        scan_pred_kernel<<<512, TB, 0, stream>>>(x, rows, cols, vals, partial);
        reduce_chunk_kernel<<<rgrid, 256, 0, stream>>>(partial, mask, out);
    } else {
        spmm_chunk_kernel<<<BATCH * CHUNKS, BLOCK, 0, stream>>>(x, rows, cols, vals, mask, out);
    }
}

// Round 8
// 205.504 us; speedup vs baseline: 1.0384x; 1.0384x over previous
//
#include <hip/hip_runtime.h>

// Problem constants
#define BATCH 32
#define CCH 3
#define HW_TEX (512 * 512)
#define N_TEX (HW_TEX * CCH)          // 786432 per-sample flat texture (channels-last)
#define OH 128
#define OW 64
#define P_OUT (OH * OW)               // 8192
#define M_OUT (P_OUT * CCH)           // 24576 rows per sample (channels-last)
#define NNZ 98304
#define OUT_ELEMS (BATCH * M_OUT)     // 786432

// Geometry (R6-proven): grid 256 (1 block/CU), per XCD 32 slots = 4 chunks x 8 segs.
#define NCH 4                          // row chunks per sample
#define RPCH (M_OUT / NCH)             // 6144 rows -> 24 KB LDS
#define NE 8                           // nnz segments
#define SEGE (NNZ / NE)                // 12288 nnz per block-round
#define TB 1024                        // threads -> 12 nnz/thread/round
#define NROUND 4                       // sample phases per XCD

#define WS_NEED ((size_t)BATCH * NCH * NE * RPCH * 4)   // 25.17 MB

// ---------- scan: chunk-specialized, PREDICATED gather, XCD-sample-phased ----
// blk: xcd = blk&7, slot = blk>>3 -> chunk c = slot&3, seg e = slot>>2.
// Round rnd: all 32 blocks of an XCD scan sample s = rnd*8+xcd (L2-resident).
// Index loads stay unconditional+batched (full MLP); gather + ds_add are
// exec-mask predicated so out-of-chunk lanes issue ZERO L2 requests.
__global__ __launch_bounds__(TB) void scan_pred8_kernel(
    const float* __restrict__ x,
    const int*   __restrict__ rows,
    const int*   __restrict__ cols,
    const float* __restrict__ vals,
    float* __restrict__ partial) {
    __shared__ __align__(16) float acc[RPCH];

    const int blk  = blockIdx.x;
    const int xcd  = blk & 7;
    const int slot = blk >> 3;
    const int c    = slot & (NCH - 1);
    const int e    = slot >> 2;
    const int t    = threadIdx.x;
    const int rbase = c * RPCH;

    for (int rnd = 0; rnd < NROUND; ++rnd) {
        const int s = rnd * 8 + xcd;

        // zero 24 KB: 3 x float2 per thread
        float2* acc2 = reinterpret_cast<float2*>(acc);
#pragma unroll
        for (int j = 0; j < RPCH / 2 / TB; ++j)
            acc2[t + j * TB] = make_float2(0.f, 0.f);
        __syncthreads();

        const size_t off = (size_t)s * NNZ + (size_t)e * SEGE;
        const int4*   r4 = reinterpret_cast<const int4*>(rows + off);
        const int4*   c4 = reinterpret_cast<const int4*>(cols + off);
        const float4* v4 = reinterpret_cast<const float4*>(vals + off);
        const float*  xs = x + (size_t)s * N_TEX;

        // Unconditional batched index loads: 9 vector loads -> full MLP
        int4 r[3], cc[3]; float4 v[3];
#pragma unroll
        for (int j = 0; j < 3; ++j) {
            r[j]  = r4[j * TB + t];
            cc[j] = c4[j * TB + t];
            v[j]  = v4[j * TB + t];
        }

#pragma unroll
        for (int j = 0; j < 3; ++j) {
            int   ri[4] = {r[j].x, r[j].y, r[j].z, r[j].w};
            int   ci[4] = {cc[j].x, cc[j].y, cc[j].z, cc[j].w};
            float vi[4] = {v[j].x, v[j].y, v[j].z, v[j].w};
#pragma unroll
            for (int k = 0; k < 4; ++k) {
                unsigned lr = (unsigned)(ri[k] - rbase);
                if (lr < (unsigned)RPCH) {     // exec-masked: inactive lanes
                    int gi = (ci[k] % CCH) * HW_TEX + ci[k] / CCH;
                    atomicAdd(&acc[lr], vi[k] * xs[gi]);  // no requests issued
                }
            }
        }
        __syncthreads();

        // dump 24 KB partial, coalesced float2
        float2* pp = reinterpret_cast<float2*>(
            partial + (((size_t)s * NCH + c) * NE + e) * RPCH);
#pragma unroll
        for (int j = 0; j < RPCH / 2 / TB; ++j)
            pp[t + j * TB] = acc2[t + j * TB];
        __syncthreads();
    }
}

// ---------- reduce: sum NE partials per (s,chunk,row), CHW transform, mask --
__global__ __launch_bounds__(256) void reduce_chunk_kernel(
    const float* __restrict__ partial,
    const float* __restrict__ mask,
    float* __restrict__ out) {
    int tid = blockIdx.x * 256 + threadIdx.x;       // over OUT_ELEMS/4
    if (tid >= OUT_ELEMS / 4) return;
    int s    = tid / (M_OUT / 4);
    int rcl4 = (tid % (M_OUT / 4)) * 4;             // 4 consecutive channels-last rows
    int c    = rcl4 / RPCH;                         // chunk (RPCH % 4 == 0)
    int lr4  = rcl4 % RPCH;

    const float4* pp = reinterpret_cast<const float4*>(
        partial + (((size_t)s * NCH + c) * NE) * RPCH + lr4);
    float4 sum = make_float4(0.f, 0.f, 0.f, 0.f);
#pragma unroll
    for (int e = 0; e < NE; ++e) {
        float4 p = pp[(size_t)e * (RPCH / 4)];
        sum.x += p.x; sum.y += p.y; sum.z += p.z; sum.w += p.w;
    }
    float* ob = out + (size_t)s * M_OUT;
    ob[(rcl4 + 0) % CCH * P_OUT + (rcl4 + 0) / CCH] = sum.x;
    ob[(rcl4 + 1) % CCH * P_OUT + (rcl4 + 1) / CCH] = sum.y;
    ob[(rcl4 + 2) % CCH * P_OUT + (rcl4 + 2) / CCH] = sum.z;
    ob[(rcl4 + 3) % CCH * P_OUT + (rcl4 + 3) / CCH] = sum.w;
    reinterpret_cast<float4*>(out + OUT_ELEMS)[tid] =
        reinterpret_cast<const float4*>(mask)[tid];
}

// ---------- fallback (R2): no workspace needed ------------------------------
#define CHUNKS 8
#define RPC (M_OUT / CHUNKS)
#define BLOCK 1024
__global__ __launch_bounds__(BLOCK) void spmm_chunk_kernel(
    const float* __restrict__ x,
    const int*   __restrict__ rows,
    const int*   __restrict__ cols,
    const float* __restrict__ vals,
    const float* __restrict__ mask,
    float* __restrict__ out) {
    __shared__ float acc[RPC];
    const int blk = blockIdx.x;
    const int s   = blk / CHUNKS;
    const int c   = blk % CHUNKS;
    const int t   = threadIdx.x;
    const int rbase = c * RPC;
#pragma unroll
    for (int j = 0; j < RPC / BLOCK; ++j) acc[t + j * BLOCK] = 0.0f;
    __syncthreads();
    const int*   rs = rows + (size_t)s * NNZ;
    const int*   cs = cols + (size_t)s * NNZ;
    const float* vs = vals + (size_t)s * NNZ;
    const float* xs = x    + (size_t)s * N_TEX;
#pragma unroll 4
    for (int i = t; i < NNZ; i += BLOCK) {
        int r = rs[i];
        unsigned lr = (unsigned)(r - rbase);
        if (lr < (unsigned)RPC) {
            int   col = cs[i];
            float v   = vs[i];
            atomicAdd(&acc[lr], v * xs[(col % CCH) * HW_TEX + col / CCH]);
        }
    }
    __syncthreads();
    const size_t outbase = (size_t)s * M_OUT;
#pragma unroll
    for (int ch = 0; ch < CCH; ++ch)
        out[outbase + (size_t)ch * P_OUT + c * (P_OUT / CHUNKS) + t] = acc[t * CCH + ch];
    {
        float* mout = out + OUT_ELEMS;
        const int base = blk * RPC;
#pragma unroll
        for (int j = 0; j < RPC / BLOCK; ++j)
            mout[base + j * BLOCK + t] = mask[base + j * BLOCK + t];
    }
}

extern "C" void kernel_launch(void* const* d_in, const int* in_sizes, int n_in,
                              void* d_out, int out_size, void* d_ws, size_t ws_size,
                              hipStream_t stream) {
    const float* x    = (const float*)d_in[0];
    const int*   rows = (const int*)  d_in[1];
    const int*   cols = (const int*)  d_in[2];
    const float* vals = (const float*)d_in[3];
    const float* mask = (const float*)d_in[4];
    float* out = (float*)d_out;
    int rgrid = (OUT_ELEMS / 4 + 255) / 256;   // 768

    if (ws_size >= WS_NEED) {
        float* partial = (float*)d_ws;
        scan_pred8_kernel<<<256, TB, 0, stream>>>(x, rows, cols, vals, partial);
        reduce_chunk_kernel<<<rgrid, 256, 0, stream>>>(partial, mask, out);
    } else {
        spmm_chunk_kernel<<<BATCH * CHUNKS, BLOCK, 0, stream>>>(x, rows, cols, vals, mask, out);
    }
}